// Round 1
// baseline (1664.717 us; speedup 1.0000x reference)
//
#include <hip/hip_runtime.h>
#include <math.h>

#define HIDDEN 16
#define CIN 5
#define BB 8
#define TT 12
#define HH 256
#define WW 256
#define TX 32
#define TY 8
#define HALO_X 34
#define HALO_Y 10
#define NPX (HALO_X * HALO_Y)   // 340 staged pixels
#define STRIDE 40               // shorts per px row: 80 B = 20 banks -> conflict-free phases
#define NMFMA 7                 // dense-packed K slots: 14 halves of 16

typedef __attribute__((ext_vector_type(8))) short bf16x8;   // 8 bf16 (4 VGPRs)
typedef __attribute__((ext_vector_type(4))) float floatx4;

__device__ __forceinline__ unsigned short f2bf(float f) {   // RNE fp32->bf16
    unsigned int u = __float_as_uint(f);
    u += 0x7fffu + ((u >> 16) & 1u);
    return (unsigned short)(u >> 16);
}
__device__ __forceinline__ float bf2f(unsigned short s) {
    return __uint_as_float(((unsigned int)s) << 16);
}
__device__ __forceinline__ float fast_sigmoid(float x) { return 1.0f / (1.0f + __expf(-x)); }
__device__ __forceinline__ float fast_tanh(float x) {
    float e2 = __expf(-2.0f * fabsf(x));
    float t = (1.0f - e2) / (1.0f + e2);
    return copysignf(t, x);
}

// Dense K packing into 14 half-slots of 16 (7 MFMAs of K=32 per gate):
//   slots 0..8  : h-tap t (16 h channels, ci 5..20)  -- exact fit, no pad
//   slots 9..13 : x-tap pairs (2 taps x [5ch+3pad])  -- matches the 8-short
//                 x block already staged per pixel
// Wfrag[mi][gate][lane][j]: lane holds B[k=(lane>>4)*8+j][col=lane&15].
__global__ void prep_w_kernel(const float* __restrict__ Wc,
                              unsigned short* __restrict__ Wfrag) {
    int i = blockIdx.x * 256 + threadIdx.x;
    if (i >= NMFMA * 4 * 64 * 8) return;
    int j    = i & 7;
    int lane = (i >> 3) & 63;
    int g    = (i >> 9) & 3;
    int mi   = i >> 11;                  // 0..6
    int k    = ((lane >> 4) << 3) + j;   // 0..31
    int col  = lane & 15;
    int o    = g * 16 + col;
    int slot = 2 * mi + (k >> 4);        // 0..13
    int w16  = k & 15;
    float w  = 0.0f;
    if (slot <= 8) {
        // h-tap slot: channel w16 -> ci_ref 5..20
        w = Wc[(o * 21 + 5 + w16) * 9 + slot];
    } else {
        int pair = slot - 9;
        int xt   = pair * 2 + (w16 >> 3);   // x-tap index
        int ch   = w16 & 7;
        if (xt < 9 && ch < 5)
            w = Wc[(o * 21 + ch) * 9 + xt];
    }
    Wfrag[i] = f2bf(w);
}

// One-time x repack: planar fp32 [b][t][c][y][x] -> channel-last bf16 [b][t][y][x][8]
__global__ void prep_x_kernel(const float* __restrict__ x,
                              unsigned short* __restrict__ xp) {
    size_t n = (size_t)blockIdx.x * 256 + threadIdx.x;
    const size_t TOTPX = (size_t)BB * TT * HH * WW;
    if (n >= TOTPX) return;
    size_t bt  = n / (size_t)(HH * WW);
    size_t pix = n - bt * (size_t)(HH * WW);
    const float* src = x + bt * (size_t)CIN * HH * WW + pix;
    unsigned short v[8];
    #pragma unroll
    for (int c = 0; c < CIN; ++c) v[c] = f2bf(src[(size_t)c * HH * WW]);
    v[5] = 0; v[6] = 0; v[7] = 0;
    *(uint4*)&xp[n * 8] = *(const uint4*)v;
}

// One ConvLSTM step: implicit-GEMM conv via MFMA + fused gates/state update.
// h: bf16 channel-last [b][y][x][16]; c: fp32 channel-last [b][y][x][16].
__global__ __launch_bounds__(256, 5)
void convlstm_step_kernel(const float* __restrict__ x, int t,
                          const unsigned short* __restrict__ xp,  // may be null
                          const unsigned short* __restrict__ h_in,
                          unsigned short* __restrict__ h_out,
                          float* __restrict__ c_state,
                          const unsigned short* __restrict__ Wfrag,
                          const float* __restrict__ bias,
                          int first, int use_xp) {
    __shared__ unsigned short tile[NPX * STRIDE];   // 27200 B

    const int tid  = threadIdx.x;
    const int lane = tid & 63;
    const int wave = tid >> 6;
    const int x0 = blockIdx.x * TX;
    const int y0 = blockIdx.y * TY;
    const int bb = blockIdx.z;

    // ---- stage tile: channel-last bf16, zero-padded halo & k-pad ----
    for (int i = tid; i < NPX; i += 256) {
        int ly = i / HALO_X;
        int lx = i - ly * HALO_X;
        int gy = y0 + ly - 1;
        int gx = x0 + lx - 1;
        bool inb = (gy >= 0 && gy < HH && gx >= 0 && gx < WW);
        unsigned short* row = &tile[i * STRIDE];
        uint4 z = {0, 0, 0, 0};
        if (inb && !first) {
            size_t hb = ((size_t)bb * HH * WW + (size_t)gy * WW + gx) * HIDDEN;
            *(uint4*)&row[0] = *(const uint4*)&h_in[hb];
            *(uint4*)&row[8] = *(const uint4*)&h_in[hb + 8];
        } else {
            *(uint4*)&row[0] = z;
            *(uint4*)&row[8] = z;
        }
        if (use_xp) {
            if (inb) {
                size_t xb = (((size_t)bb * TT + t) * (size_t)(HH * WW)
                             + (size_t)gy * WW + gx) * 8;
                *(uint4*)&row[16] = *(const uint4*)&xp[xb];
            } else {
                *(uint4*)&row[16] = z;
            }
        } else {
            #pragma unroll
            for (int ci = 0; ci < CIN; ++ci) {
                float v = 0.0f;
                if (inb) v = x[(((size_t)bb * TT + t) * CIN + ci) * (size_t)(HH * WW)
                               + (size_t)gy * WW + gx];
                row[16 + ci] = f2bf(v);
            }
            row[21] = 0; row[22] = 0; row[23] = 0;
        }
        *(uint4*)&row[24] = z;   // zero region: pad half-slot reads land here
    }
    __syncthreads();

    const int u    = lane & 15;
    const int quad = lane >> 4;

    // Per-(MFMA, quad) A-fragment offset (shorts), computed once per thread.
    // h slot (tap T, half q&1): pd(T)*STRIDE + (q&1)*8
    // x half-slot (tap T):      pd(T)*STRIDE + 16
    // pad half-slot:            +24 (zeroed region)
    int aoff[NMFMA];
    #pragma unroll
    for (int s = 0; s < 4; ++s) {                 // mi 0..3: h-taps (2s, 2s+1)
        int tap = s * 2 + (quad >> 1);
        aoff[s] = ((tap / 3) * HALO_X + (tap % 3)) * STRIDE + (quad & 1) * 8;
    }
    // mi 4: slot8 = h-tap8 (quads 0,1), slot9 = x-taps 0,1 (quads 2,3)
    aoff[4] = (quad < 2) ? (70 * STRIDE + quad * 8)
                         : ((quad - 2) * STRIDE + 16);
    // mi 5: x-taps 2..5
    { int t5 = 2 + quad;
      aoff[5] = ((t5 / 3) * HALO_X + (t5 % 3)) * STRIDE + 16; }
    // mi 6: x-taps 6,7,8 + pad (quad 3 reads zero region)
    { int t6 = (quad == 3) ? 8 : (6 + quad);
      int of6 = (quad == 3) ? 24 : 16;
      aoff[6] = ((t6 / 3) * HALO_X + (t6 % 3)) * STRIDE + of6; }

    float bg[4];
    #pragma unroll
    for (int g = 0; g < 4; ++g) bg[g] = bias[g * 16 + u];

    // 2 halves of 2 M-strips each: halves the accumulator footprint (32 vs 64)
    #pragma unroll 1
    for (int half = 0; half < 2; ++half) {
        floatx4 acc[2][4];
        int abase[2];
        #pragma unroll
        for (int mh = 0; mh < 2; ++mh) {
            int ml = half * 2 + mh;
            int m  = wave + ml * 4;
            int my = m >> 1;
            int mx = (m & 1) << 4;
            abase[mh] = (my * HALO_X + mx + u) * STRIDE;
            #pragma unroll
            for (int g = 0; g < 4; ++g)
                acc[mh][g] = (floatx4){bg[g], bg[g], bg[g], bg[g]};
        }

        #pragma unroll
        for (int mi = 0; mi < NMFMA; ++mi) {
            bf16x8 bfr[4];
            #pragma unroll
            for (int g = 0; g < 4; ++g)
                bfr[g] = *(const bf16x8*)&Wfrag[(size_t)((mi * 4 + g) * 64 + lane) * 8];
            #pragma unroll
            for (int mh = 0; mh < 2; ++mh) {
                bf16x8 af = *(const bf16x8*)&tile[abase[mh] + aoff[mi]];
                #pragma unroll
                for (int g = 0; g < 4; ++g)
                    acc[mh][g] = __builtin_amdgcn_mfma_f32_16x16x32_bf16(
                        af, bfr[g], acc[mh][g], 0, 0, 0);
            }
        }

        // ---- epilogue: gates + state update for this half's 2 strips ----
        #pragma unroll
        for (int mh = 0; mh < 2; ++mh) {
            int ml = half * 2 + mh;
            int m  = wave + ml * 4;
            int my = m >> 1;
            int mx = (m & 1) << 4;
            int py = y0 + my;
            #pragma unroll
            for (int r = 0; r < 4; ++r) {
                int pxx = x0 + mx + quad * 4 + r;
                size_t idx = ((size_t)bb * HH * WW + (size_t)py * WW + pxx) * HIDDEN + u;
                float ig = fast_sigmoid(acc[mh][0][r]);
                float fg = fast_sigmoid(acc[mh][1][r]);
                float og = fast_sigmoid(acc[mh][2][r]);
                float gg = fast_tanh(acc[mh][3][r]);
                float c_old = first ? 0.0f : c_state[idx];
                float c_new = fg * c_old + ig * gg;
                c_state[idx] = c_new;
                h_out[idx] = f2bf(og * fast_tanh(c_new));
            }
        }
    }
}

// Final 1x1 conv from bf16 channel-last h
__global__ void final_conv_kernel(const unsigned short* __restrict__ h,
                                  const float* __restrict__ Wf,
                                  const float* __restrict__ bf_,
                                  float* __restrict__ out) {
    int i = blockIdx.x * 256 + threadIdx.x;
    if (i >= BB * HH * WW) return;
    size_t base = (size_t)i * HIDDEN;
    uint4 v0 = *(const uint4*)&h[base];
    uint4 v1 = *(const uint4*)&h[base + 8];
    const unsigned short* p0 = (const unsigned short*)&v0;
    const unsigned short* p1 = (const unsigned short*)&v1;
    float s = bf_[0];
    #pragma unroll
    for (int k = 0; k < 8; ++k) s += Wf[k] * bf2f(p0[k]);
    #pragma unroll
    for (int k = 0; k < 8; ++k) s += Wf[8 + k] * bf2f(p1[k]);
    out[i] = s;
}

extern "C" void kernel_launch(void* const* d_in, const int* in_sizes, int n_in,
                              void* d_out, int out_size, void* d_ws, size_t ws_size,
                              hipStream_t stream) {
    const float* x  = (const float*)d_in[0];
    const float* Wc = (const float*)d_in[1];
    const float* bc = (const float*)d_in[2];
    const float* Wf = (const float*)d_in[3];
    const float* bf = (const float*)d_in[4];
    float* out = (float*)d_out;

    char* ws = (char*)d_ws;
    const size_t h_bytes = (size_t)BB * HH * WW * HIDDEN * 2;   // 16.78 MB
    const size_t c_bytes = (size_t)BB * HH * WW * HIDDEN * 4;   // 33.55 MB
    const size_t w_bytes = NMFMA * 4 * 64 * 8 * 2;              // 28.7 KB
    const size_t x_bytes = (size_t)BB * TT * HH * WW * 8 * 2;   // 100.7 MB

    unsigned short* h_a = (unsigned short*)(ws);
    unsigned short* h_b = (unsigned short*)(ws + h_bytes);
    float* c            = (float*)(ws + 2 * h_bytes);
    unsigned short* Wfr = (unsigned short*)(ws + 2 * h_bytes + c_bytes);
    unsigned short* xp  = (unsigned short*)(ws + 2 * h_bytes + c_bytes + w_bytes);

    const int use_xp =
        (ws_size >= 2 * h_bytes + c_bytes + w_bytes + x_bytes) ? 1 : 0;

    prep_w_kernel<<<(NMFMA * 4 * 64 * 8 + 255) / 256, 256, 0, stream>>>(Wc, Wfr);
    if (use_xp) {
        size_t totpx = (size_t)BB * TT * HH * WW;
        prep_x_kernel<<<(int)((totpx + 255) / 256), 256, 0, stream>>>(x, xp);
    }

    dim3 grid(WW / TX, HH / TY, BB);   // 2048 blocks
    dim3 block(256, 1, 1);

    const unsigned short* h_in = h_a;
    for (int t = 0; t < TT; ++t) {
        unsigned short* h_out = (t & 1) ? h_b : h_a;
        convlstm_step_kernel<<<grid, block, 0, stream>>>(
            x, t, use_xp ? xp : (const unsigned short*)0,
            h_in, h_out, c, Wfr, bc, (t == 0) ? 1 : 0, use_xp);
        h_in = h_out;
    }

    final_conv_kernel<<<(BB * HH * WW + 255) / 256, 256, 0, stream>>>(
        h_in, Wf, bf, out);
}

// Round 2
// 686.209 us; speedup vs baseline: 2.4260x; 2.4260x over previous
//
#include <hip/hip_runtime.h>
#include <hip/hip_cooperative_groups.h>
#include <math.h>

#define HIDDEN 16
#define CIN 5
#define BB 8
#define TT 12
#define HH 256
#define WW 256
#define TX 32
#define TY 8
#define HALO_X 34
#define HALO_Y 10
#define NPX (HALO_X * HALO_Y)   // 340 staged pixels
#define STRIDE 40               // shorts per px row: 80 B = 20 banks -> conflict-free phases
#define NBLK_PERSIST 1024       // 4 blocks/CU x 256 CU; each owns 2 tiles

typedef __attribute__((ext_vector_type(8))) short bf16x8;   // 8 bf16 (4 VGPRs)
typedef __attribute__((ext_vector_type(4))) float floatx4;

namespace cg = cooperative_groups;

__device__ __forceinline__ unsigned short f2bf(float f) {   // RNE fp32->bf16
    unsigned int u = __float_as_uint(f);
    u += 0x7fffu + ((u >> 16) & 1u);
    return (unsigned short)(u >> 16);
}
__device__ __forceinline__ float bf2f(unsigned short s) {
    return __uint_as_float(((unsigned int)s) << 16);
}
__device__ __forceinline__ float fast_sigmoid(float x) { return 1.0f / (1.0f + __expf(-x)); }
__device__ __forceinline__ float fast_tanh(float x) {
    float e2 = __expf(-2.0f * fabsf(x));
    float t = (1.0f - e2) / (1.0f + e2);
    return copysignf(t, x);
}

// Pack W_cell [64][21][3][3] into exact B-fragment layout for
// mfma_f32_16x16x32_bf16: Wfrag[tap][gate][lane][j]; lane holds
// B[k=(lane>>4)*8+j][col=lane&15], col = hidden unit, N-tile = gate.
// k-order: 0..15 = h units (ci_ref 5+k), 16..20 = x chans, 21..31 = 0.
__global__ void prep_w_kernel(const float* __restrict__ Wc,
                              unsigned short* __restrict__ Wfrag) {
    int i = blockIdx.x * 256 + threadIdx.x;
    if (i >= 9 * 4 * 64 * 8) return;
    int j    = i & 7;
    int lane = (i >> 3) & 63;
    int g    = (i >> 9) & 3;
    int tap  = i >> 11;
    int k    = ((lane >> 4) << 3) + j;
    int col  = lane & 15;
    int o    = g * 16 + col;
    float w  = 0.0f;
    if (k < 21) {
        int ci_ref = (k < 16) ? (5 + k) : (k - 16);
        w = Wc[(o * 21 + ci_ref) * 9 + tap];
    }
    Wfrag[i] = f2bf(w);
}

// One-time x repack: planar fp32 [b][t][c][y][x] -> channel-last bf16 [b][t][y][x][8]
__global__ void prep_x_kernel(const float* __restrict__ x,
                              unsigned short* __restrict__ xp) {
    size_t n = (size_t)blockIdx.x * 256 + threadIdx.x;
    const size_t TOTPX = (size_t)BB * TT * HH * WW;
    if (n >= TOTPX) return;
    size_t bt  = n / (size_t)(HH * WW);
    size_t pix = n - bt * (size_t)(HH * WW);
    const float* src = x + bt * (size_t)CIN * HH * WW + pix;
    unsigned short v[8];
    #pragma unroll
    for (int c = 0; c < CIN; ++c) v[c] = f2bf(src[(size_t)c * HH * WW]);
    v[5] = 0; v[6] = 0; v[7] = 0;
    *(uint4*)&xp[n * 8] = *(const uint4*)v;
}

// ---------------------------------------------------------------------------
// Persistent cooperative kernel: all TT steps in one launch.
// c-state lives in registers (block-local by construction); h round-trips
// through global with grid.sync() between steps; final 1x1 conv fused at
// t == TT-1 via 16-lane shfl reduce.
// ---------------------------------------------------------------------------
__global__ __launch_bounds__(256, 4)
void convlstm_persistent_kernel(const float* __restrict__ x,
                                const unsigned short* __restrict__ xp,  // may be null
                                unsigned short* __restrict__ ha,
                                unsigned short* __restrict__ hbuf,
                                const unsigned short* __restrict__ Wfrag,
                                const float* __restrict__ bias,
                                const float* __restrict__ Wf,
                                const float* __restrict__ bfin,
                                float* __restrict__ out,
                                int use_xp) {
    __shared__ unsigned short tile[NPX * STRIDE];   // 27200 B
    cg::grid_group grid = cg::this_grid();

    const int tid  = threadIdx.x;
    const int lane = tid & 63;
    const int wave = tid >> 6;
    const int u    = lane & 15;
    const int quad = lane >> 4;

    float bg[4];
    #pragma unroll
    for (int g = 0; g < 4; ++g) bg[g] = bias[g * 16 + u];
    const float wfu = Wf[u];
    const float bf0 = bfin[0];

    // c-state registers: [tile][mh][r], split into two static arrays for the
    // two halves (half is a runtime unroll-1 loop var -> no runtime indexing).
    float cA[2][2][4];
    float cB[2][2][4];
    #pragma unroll
    for (int a = 0; a < 2; ++a)
        #pragma unroll
        for (int m = 0; m < 2; ++m)
            #pragma unroll
            for (int r = 0; r < 4; ++r) { cA[a][m][r] = 0.0f; cB[a][m][r] = 0.0f; }

    #pragma unroll 1
    for (int t = 0; t < TT; ++t) {
        const unsigned short* h_in  = (t & 1) ? ha : hbuf;
        unsigned short*       h_out = (t & 1) ? hbuf : ha;
        const int first = (t == 0);
        const int last  = (t == TT - 1);

        #pragma unroll
        for (int tl = 0; tl < 2; ++tl) {
            const int n  = (int)blockIdx.x + tl * NBLK_PERSIST;   // 0..2047
            const int x0 = (n & 7) * TX;
            const int y0 = ((n >> 3) & 31) * TY;
            const int bb = n >> 8;

            if (t > 0 || tl > 0) __syncthreads();   // protect LDS reuse

            // ---- stage tile: channel-last bf16, zero-padded halo & k-pad ----
            for (int i = tid; i < NPX; i += 256) {
                int ly = i / HALO_X;
                int lx = i - ly * HALO_X;
                int gy = y0 + ly - 1;
                int gx = x0 + lx - 1;
                bool inb = (gy >= 0 && gy < HH && gx >= 0 && gx < WW);
                unsigned short* row = &tile[i * STRIDE];
                uint4 z = {0, 0, 0, 0};
                if (inb && !first) {
                    size_t hbase = ((size_t)bb * HH * WW + (size_t)gy * WW + gx) * HIDDEN;
                    *(uint4*)&row[0] = *(const uint4*)&h_in[hbase];
                    *(uint4*)&row[8] = *(const uint4*)&h_in[hbase + 8];
                } else {
                    *(uint4*)&row[0] = z;
                    *(uint4*)&row[8] = z;
                }
                if (use_xp) {
                    if (inb) {
                        size_t xb = (((size_t)bb * TT + t) * (size_t)(HH * WW)
                                     + (size_t)gy * WW + gx) * 8;
                        *(uint4*)&row[16] = *(const uint4*)&xp[xb];
                    } else {
                        *(uint4*)&row[16] = z;
                    }
                } else {
                    #pragma unroll
                    for (int ci = 0; ci < CIN; ++ci) {
                        float v = 0.0f;
                        if (inb) v = x[(((size_t)bb * TT + t) * CIN + ci) * (size_t)(HH * WW)
                                       + (size_t)gy * WW + gx];
                        row[16 + ci] = f2bf(v);
                    }
                    row[21] = 0; row[22] = 0; row[23] = 0;
                }
                *(uint4*)&row[24] = z;
            }
            __syncthreads();

            // 2 halves of 2 M-strips each: halves the accumulator footprint
            #pragma unroll 1
            for (int half = 0; half < 2; ++half) {
                floatx4 acc[2][4];
                int abase[2];
                #pragma unroll
                for (int mh = 0; mh < 2; ++mh) {
                    int ml = half * 2 + mh;
                    int m  = wave + ml * 4;
                    int my = m >> 1;
                    int mx = (m & 1) << 4;
                    abase[mh] = (my * HALO_X + mx + u) * STRIDE + quad * 8;
                    #pragma unroll
                    for (int g = 0; g < 4; ++g)
                        acc[mh][g] = (floatx4){bg[g], bg[g], bg[g], bg[g]};
                }

                #pragma unroll 3
                for (int tap = 0; tap < 9; ++tap) {
                    int ky = tap / 3;
                    int kx = tap - ky * 3;
                    int toff = (ky * HALO_X + kx) * STRIDE;
                    bf16x8 bfr[4];
                    #pragma unroll
                    for (int g = 0; g < 4; ++g)
                        bfr[g] = *(const bf16x8*)&Wfrag[(size_t)((tap * 4 + g) * 64 + lane) * 8];
                    #pragma unroll
                    for (int mh = 0; mh < 2; ++mh) {
                        bf16x8 af = *(const bf16x8*)&tile[abase[mh] + toff];
                        #pragma unroll
                        for (int g = 0; g < 4; ++g)
                            acc[mh][g] = __builtin_amdgcn_mfma_f32_16x16x32_bf16(
                                af, bfr[g], acc[mh][g], 0, 0, 0);
                    }
                }

                // ---- epilogue: gates + register c update ----
                #pragma unroll
                for (int mh = 0; mh < 2; ++mh) {
                    int ml = half * 2 + mh;
                    int m  = wave + ml * 4;
                    int my = m >> 1;
                    int mx = (m & 1) << 4;
                    int py = y0 + my;
                    #pragma unroll
                    for (int r = 0; r < 4; ++r) {
                        int pxx = x0 + mx + quad * 4 + r;
                        float ig = fast_sigmoid(acc[mh][0][r]);
                        float fg = fast_sigmoid(acc[mh][1][r]);
                        float og = fast_sigmoid(acc[mh][2][r]);
                        float gg = fast_tanh(acc[mh][3][r]);
                        float c_old = half ? cB[tl][mh][r] : cA[tl][mh][r];
                        float c_new = fg * c_old + ig * gg;
                        if (half) cB[tl][mh][r] = c_new; else cA[tl][mh][r] = c_new;
                        float hval = og * fast_tanh(c_new);
                        if (last) {
                            // fused 1x1 conv: sum over 16 channels (lanes of this quad)
                            float s = wfu * hval;
                            s += __shfl_xor(s, 1);
                            s += __shfl_xor(s, 2);
                            s += __shfl_xor(s, 4);
                            s += __shfl_xor(s, 8);
                            if (u == 0)
                                out[(size_t)bb * HH * WW + (size_t)py * WW + pxx] = s + bf0;
                        } else {
                            size_t idx = ((size_t)bb * HH * WW + (size_t)py * WW + pxx)
                                         * HIDDEN + u;
                            h_out[idx] = f2bf(hval);
                        }
                    }
                }
            }
        }
        if (t != TT - 1) grid.sync();
    }
}

// ---------------------------------------------------------------------------
// Legacy per-step path (round-0, proven) — fallback if cooperative launch
// is unavailable.
// ---------------------------------------------------------------------------
__global__ __launch_bounds__(256, 5)
void convlstm_step_kernel(const float* __restrict__ x, int t,
                          const unsigned short* __restrict__ xp,  // may be null
                          const unsigned short* __restrict__ h_in,
                          unsigned short* __restrict__ h_out,
                          float* __restrict__ c_state,
                          const unsigned short* __restrict__ Wfrag,
                          const float* __restrict__ bias,
                          int first, int use_xp) {
    __shared__ unsigned short tile[NPX * STRIDE];   // 27200 B

    const int tid  = threadIdx.x;
    const int lane = tid & 63;
    const int wave = tid >> 6;
    const int x0 = blockIdx.x * TX;
    const int y0 = blockIdx.y * TY;
    const int bb = blockIdx.z;

    for (int i = tid; i < NPX; i += 256) {
        int ly = i / HALO_X;
        int lx = i - ly * HALO_X;
        int gy = y0 + ly - 1;
        int gx = x0 + lx - 1;
        bool inb = (gy >= 0 && gy < HH && gx >= 0 && gx < WW);
        unsigned short* row = &tile[i * STRIDE];
        uint4 z = {0, 0, 0, 0};
        if (inb && !first) {
            size_t hbase = ((size_t)bb * HH * WW + (size_t)gy * WW + gx) * HIDDEN;
            *(uint4*)&row[0] = *(const uint4*)&h_in[hbase];
            *(uint4*)&row[8] = *(const uint4*)&h_in[hbase + 8];
        } else {
            *(uint4*)&row[0] = z;
            *(uint4*)&row[8] = z;
        }
        if (use_xp) {
            if (inb) {
                size_t xb = (((size_t)bb * TT + t) * (size_t)(HH * WW)
                             + (size_t)gy * WW + gx) * 8;
                *(uint4*)&row[16] = *(const uint4*)&xp[xb];
            } else {
                *(uint4*)&row[16] = z;
            }
        } else {
            #pragma unroll
            for (int ci = 0; ci < CIN; ++ci) {
                float v = 0.0f;
                if (inb) v = x[(((size_t)bb * TT + t) * CIN + ci) * (size_t)(HH * WW)
                               + (size_t)gy * WW + gx];
                row[16 + ci] = f2bf(v);
            }
            row[21] = 0; row[22] = 0; row[23] = 0;
        }
        *(uint4*)&row[24] = z;
    }
    __syncthreads();

    const int u    = lane & 15;
    const int quad = lane >> 4;

    float bg[4];
    #pragma unroll
    for (int g = 0; g < 4; ++g) bg[g] = bias[g * 16 + u];

    #pragma unroll 1
    for (int half = 0; half < 2; ++half) {
        floatx4 acc[2][4];
        int abase[2];
        #pragma unroll
        for (int mh = 0; mh < 2; ++mh) {
            int ml = half * 2 + mh;
            int m  = wave + ml * 4;
            int my = m >> 1;
            int mx = (m & 1) << 4;
            abase[mh] = (my * HALO_X + mx + u) * STRIDE + quad * 8;
            #pragma unroll
            for (int g = 0; g < 4; ++g)
                acc[mh][g] = (floatx4){bg[g], bg[g], bg[g], bg[g]};
        }

        #pragma unroll 3
        for (int tap = 0; tap < 9; ++tap) {
            int ky = tap / 3;
            int kx = tap - ky * 3;
            int toff = (ky * HALO_X + kx) * STRIDE;
            bf16x8 bfr[4];
            #pragma unroll
            for (int g = 0; g < 4; ++g)
                bfr[g] = *(const bf16x8*)&Wfrag[(size_t)((tap * 4 + g) * 64 + lane) * 8];
            #pragma unroll
            for (int mh = 0; mh < 2; ++mh) {
                bf16x8 af = *(const bf16x8*)&tile[abase[mh] + toff];
                #pragma unroll
                for (int g = 0; g < 4; ++g)
                    acc[mh][g] = __builtin_amdgcn_mfma_f32_16x16x32_bf16(
                        af, bfr[g], acc[mh][g], 0, 0, 0);
            }
        }

        #pragma unroll
        for (int mh = 0; mh < 2; ++mh) {
            int ml = half * 2 + mh;
            int m  = wave + ml * 4;
            int my = m >> 1;
            int mx = (m & 1) << 4;
            int py = y0 + my;
            #pragma unroll
            for (int r = 0; r < 4; ++r) {
                int pxx = x0 + mx + quad * 4 + r;
                size_t idx = ((size_t)bb * HH * WW + (size_t)py * WW + pxx) * HIDDEN + u;
                float ig = fast_sigmoid(acc[mh][0][r]);
                float fg = fast_sigmoid(acc[mh][1][r]);
                float og = fast_sigmoid(acc[mh][2][r]);
                float gg = fast_tanh(acc[mh][3][r]);
                float c_old = first ? 0.0f : c_state[idx];
                float c_new = fg * c_old + ig * gg;
                c_state[idx] = c_new;
                h_out[idx] = f2bf(og * fast_tanh(c_new));
            }
        }
    }
}

// Final 1x1 conv from bf16 channel-last h (legacy path only)
__global__ void final_conv_kernel(const unsigned short* __restrict__ h,
                                  const float* __restrict__ Wf,
                                  const float* __restrict__ bf_,
                                  float* __restrict__ out) {
    int i = blockIdx.x * 256 + threadIdx.x;
    if (i >= BB * HH * WW) return;
    size_t base = (size_t)i * HIDDEN;
    uint4 v0 = *(const uint4*)&h[base];
    uint4 v1 = *(const uint4*)&h[base + 8];
    const unsigned short* p0 = (const unsigned short*)&v0;
    const unsigned short* p1 = (const unsigned short*)&v1;
    float s = bf_[0];
    #pragma unroll
    for (int k = 0; k < 8; ++k) s += Wf[k] * bf2f(p0[k]);
    #pragma unroll
    for (int k = 0; k < 8; ++k) s += Wf[8 + k] * bf2f(p1[k]);
    out[i] = s;
}

extern "C" void kernel_launch(void* const* d_in, const int* in_sizes, int n_in,
                              void* d_out, int out_size, void* d_ws, size_t ws_size,
                              hipStream_t stream) {
    const float* x  = (const float*)d_in[0];
    const float* Wc = (const float*)d_in[1];
    const float* bc = (const float*)d_in[2];
    const float* Wf = (const float*)d_in[3];
    const float* bf = (const float*)d_in[4];
    float* out = (float*)d_out;

    char* ws = (char*)d_ws;
    const size_t h_bytes = (size_t)BB * HH * WW * HIDDEN * 2;   // 16.78 MB
    const size_t c_bytes = (size_t)BB * HH * WW * HIDDEN * 4;   // 33.55 MB
    const size_t w_bytes = 9 * 4 * 64 * 8 * 2;                  // 36.9 KB
    const size_t x_bytes = (size_t)BB * TT * HH * WW * 8 * 2;   // 100.7 MB

    unsigned short* h_a = (unsigned short*)(ws);
    unsigned short* h_b = (unsigned short*)(ws + h_bytes);
    float* c            = (float*)(ws + 2 * h_bytes);
    unsigned short* Wfr = (unsigned short*)(ws + 2 * h_bytes + c_bytes);
    unsigned short* xp  = (unsigned short*)(ws + 2 * h_bytes + c_bytes + w_bytes);

    const int use_xp =
        (ws_size >= 2 * h_bytes + c_bytes + w_bytes + x_bytes) ? 1 : 0;

    prep_w_kernel<<<(9 * 4 * 64 * 8 + 255) / 256, 256, 0, stream>>>(Wc, Wfr);
    if (use_xp) {
        size_t totpx = (size_t)BB * TT * HH * WW;
        prep_x_kernel<<<(int)((totpx + 255) / 256), 256, 0, stream>>>(x, xp);
    }

    // Preferred path: persistent cooperative kernel (c-state in registers).
    int occ = 0;
    hipOccupancyMaxActiveBlocksPerMultiprocessor(&occ, convlstm_persistent_kernel,
                                                 256, 0);
    bool done = false;
    if (occ >= 4) {
        const unsigned short* xp_arg = use_xp ? xp : (const unsigned short*)0;
        int use_xp_arg = use_xp;
        void* kargs[] = {
            (void*)&x, (void*)&xp_arg, (void*)&h_a, (void*)&h_b,
            (void*)&Wfr, (void*)&bc, (void*)&Wf, (void*)&bf,
            (void*)&out, (void*)&use_xp_arg
        };
        if (hipLaunchCooperativeKernel((const void*)convlstm_persistent_kernel,
                                       dim3(NBLK_PERSIST, 1, 1), dim3(256, 1, 1),
                                       kargs, 0, stream) == hipSuccess)
            done = true;
    }

    if (!done) {
        // Legacy per-step path (round-0 behavior)
        dim3 grid(WW / TX, HH / TY, BB);   // 2048 blocks
        dim3 block(256, 1, 1);
        const unsigned short* h_in = h_a;
        for (int t = 0; t < TT; ++t) {
            unsigned short* h_out = (t & 1) ? h_b : h_a;
            convlstm_step_kernel<<<grid, block, 0, stream>>>(
                x, t, use_xp ? xp : (const unsigned short*)0,
                h_in, h_out, c, Wfr, bc, (t == 0) ? 1 : 0, use_xp);
            h_in = h_out;
        }
        final_conv_kernel<<<(BB * HH * WW + 255) / 256, 256, 0, stream>>>(
            h_in, Wf, bf, out);
    }
}